// Round 1
// baseline (8088.367 us; speedup 1.0000x reference)
//
#include <hip/hip_runtime.h>
#include <hip/hip_bf16.h>

// MultilayerPCN: predictive-coding inference loop.
// NODES = [2048, 4096, 8192], B = 256, n_iters = 8 (hardcoded; host cannot read
// device scalar under graph capture), LAMB = 0.5, output = 8 fp32 energies.
//
// Per iteration (all fused into 4 GEMM epilogues):
//   G1: c = e1 @ W0        -> nv0 = relu(v0 + lr*((mem-v0) - 0.5*sign(v0) + tanh'(v0)*c))
//                             T0 = tanh(nv0); loss += sum((nv0-mem)^2)
//   G2: c = e2 @ W1        -> nv1 = relu(v1 + lr*(-e1 + tanh'(v1)*c)); T1 = tanh(nv1)
//   G3: c = T0 @ W0^T      -> ne1 = nv1 - c; loss += sum(ne1^2)
//   G4: c = T1 @ W1^T      -> ne2 = batch_inp - c; loss += sum(ne2^2)
// Workspace use: ~25.3 MB fp32.

static constexpr float LOSS_SCALE = 100.0f / 256.0f;

__device__ __forceinline__ float signf_(float x) {
    return (x > 0.f) ? 1.f : ((x < 0.f) ? -1.f : 0.f);
}

// ---------------- small helper kernels ----------------
__global__ void k_zero(float* p, int n) {
    int i = blockIdx.x * blockDim.x + threadIdx.x;
    if (i < n) p[i] = 0.f;
}

__global__ void k_fill_v0(float* __restrict__ v0, const float* __restrict__ memory,
                          int n, int mask) {
    int i = blockIdx.x * blockDim.x + threadIdx.x;
    if (i < n) v0[i] = memory[i & mask];
}

__global__ void k_tanh(float* __restrict__ dst, const float* __restrict__ src, int n) {
    int i = blockIdx.x * blockDim.x + threadIdx.x;
    if (i < n) dst[i] = tanhf(src[i]);
}

// out[i] = sum_j x[j] * W[i*K + j]  (one block per output row)
__global__ void k_rowdot(const float* __restrict__ x, const float* __restrict__ W,
                         float* __restrict__ out, int K) {
    int i = blockIdx.x;
    const float* w = W + (size_t)i * K;
    float s = 0.f;
    for (int j = threadIdx.x; j < K; j += 256) s += x[j] * w[j];
    __shared__ float red[256];
    red[threadIdx.x] = s;
    __syncthreads();
    for (int st = 128; st > 0; st >>= 1) {
        if (threadIdx.x < st) red[threadIdx.x] += red[threadIdx.x + st];
        __syncthreads();
    }
    if (threadIdx.x == 0) out[i] = red[0];
}

__global__ void k_bcast_v1_e1(float* __restrict__ v1, float* __restrict__ e1,
                              const float* __restrict__ r1, int n, int mask) {
    int i = blockIdx.x * blockDim.x + threadIdx.x;
    if (i < n) { v1[i] = r1[i & mask]; e1[i] = 0.f; }
}

__global__ void k_e2_init(float* __restrict__ e2, const float* __restrict__ inp,
                          const float* __restrict__ r2, int n, int mask) {
    int i = blockIdx.x * blockDim.x + threadIdx.x;
    if (i < n) e2[i] = inp[i] - r2[i & mask];
}

// ---------------- fused GEMM ----------------
// C = A(256 x K) * B, 64x64 tile, BK=16, 256 threads, 4x4 per thread.
// BT=0: B is K x N row-major (e @ W case).  BT=1: B is N x K row-major (t @ W^T case).
// EPI selects the fused epilogue (see header comment).
template <int BT, int EPI>
__global__ __launch_bounds__(256) void gemm_fused(
    const float* __restrict__ A, const float* __restrict__ Bm, int N, int K,
    const float* __restrict__ x0, const float* __restrict__ x1,
    float* __restrict__ y0, float* __restrict__ y1,
    float* __restrict__ loss_acc, const float* __restrict__ lr_ptr)
{
    __shared__ float As[16][68];   // [k][m], padded
    __shared__ float Bs[16][68];   // [k][n], padded
    __shared__ float red[256];

    const int tid = threadIdx.x;
    const int tx = tid & 15, ty = tid >> 4;
    const int row0 = blockIdx.y * 64, col0 = blockIdx.x * 64;

    const int aRow = tid >> 2, aCol = (tid & 3) << 2;

    float acc[4][4] = {};

    for (int k0 = 0; k0 < K; k0 += 16) {
        // stage A tile (64 x 16), transposed into As[k][m]
        float4 a = *(const float4*)&A[(size_t)(row0 + aRow) * K + k0 + aCol];
        As[aCol + 0][aRow] = a.x;
        As[aCol + 1][aRow] = a.y;
        As[aCol + 2][aRow] = a.z;
        As[aCol + 3][aRow] = a.w;
        if (BT == 0) {
            const int bRow = tid >> 4, bCol = (tid & 15) << 2;
            float4 b = *(const float4*)&Bm[(size_t)(k0 + bRow) * N + col0 + bCol];
            *(float4*)&Bs[bRow][bCol] = b;
        } else {
            const int nRow = tid >> 2, kCol = (tid & 3) << 2;
            float4 b = *(const float4*)&Bm[(size_t)(col0 + nRow) * K + k0 + kCol];
            Bs[kCol + 0][nRow] = b.x;
            Bs[kCol + 1][nRow] = b.y;
            Bs[kCol + 2][nRow] = b.z;
            Bs[kCol + 3][nRow] = b.w;
        }
        __syncthreads();
#pragma unroll
        for (int kk = 0; kk < 16; ++kk) {
            float4 av = *(const float4*)&As[kk][ty << 2];
            float4 bv = *(const float4*)&Bs[kk][tx << 2];
            float aa[4] = {av.x, av.y, av.z, av.w};
            float bb[4] = {bv.x, bv.y, bv.z, bv.w};
#pragma unroll
            for (int i = 0; i < 4; ++i)
#pragma unroll
                for (int j = 0; j < 4; ++j)
                    acc[i][j] = fmaf(aa[i], bb[j], acc[i][j]);
        }
        __syncthreads();
    }

    float lr = 0.f;
    if (EPI == 1 || EPI == 2) lr = *lr_ptr;
    float lsum = 0.f;

#pragma unroll
    for (int i = 0; i < 4; ++i) {
#pragma unroll
        for (int j = 0; j < 4; ++j) {
            const int m = row0 + (ty << 2) + i;
            const int n = col0 + (tx << 2) + j;
            const size_t idx = (size_t)m * N + n;
            const float c = acc[i][j];
            if (EPI == 1) {
                // update v0; T0 = tanh(nv0); ne0^2 into loss
                float v = x0[idx];          // v0 (pre-update)
                float mem = x1[n];          // memory
                float t = tanhf(v), td = 1.f - t * t;
                float d0 = (mem - v) - 0.5f * signf_(v) + td * c;
                float nv = v + lr * d0;
                nv = nv > 0.f ? nv : 0.f;
                y0[idx] = nv;               // v0 (in place)
                y1[idx] = tanhf(nv);        // T0
                float ne0 = nv - mem;
                lsum += ne0 * ne0;
            } else if (EPI == 2) {
                // update v1; T1 = tanh(nv1)
                float v = x0[idx];          // v1 (pre-update)
                float e1v = x1[idx];        // e1 (pre-update)
                float t = tanhf(v), td = 1.f - t * t;
                float d1 = -e1v + td * c;
                float nv = v + lr * d1;
                nv = nv > 0.f ? nv : 0.f;
                y0[idx] = nv;               // v1 (in place)
                y1[idx] = tanhf(nv);        // T1
            } else if (EPI == 3) {
                // ne1 = nv1 - pred1
                float ne1 = x0[idx] - c;    // x0 = v1 (updated)
                y0[idx] = ne1;              // e1
                lsum += ne1 * ne1;
            } else {
                // ne2 = batch_inp - pred2
                float ne2 = x0[idx] - c;    // x0 = batch_inp
                y0[idx] = ne2;              // e2
                lsum += ne2 * ne2;
            }
        }
    }

    if (EPI != 2) {
        red[tid] = lsum;
        __syncthreads();
        for (int st = 128; st > 0; st >>= 1) {
            if (tid < st) red[tid] += red[tid + st];
            __syncthreads();
        }
        if (tid == 0) atomicAdd(loss_acc, red[0] * LOSS_SCALE);
    }
}

extern "C" void kernel_launch(void* const* d_in, const int* in_sizes, int n_in,
                              void* d_out, int out_size, void* d_ws, size_t ws_size,
                              hipStream_t stream)
{
    const float* batch_inp = (const float*)d_in[0]; // (256, 8192)
    const float* W0        = (const float*)d_in[1]; // (4096, 2048)
    const float* W1        = (const float*)d_in[2]; // (8192, 4096)
    const float* memory    = (const float*)d_in[3]; // (2048,)
    const float* lr_ptr    = (const float*)d_in[5]; // scalar 0.05
    float* out = (float*)d_out;                     // 8 losses

    const int n0 = 2048, n1 = 4096, n2 = 8192, Bn = 256;

    float* ws = (float*)d_ws;
    float* v0 = ws;                  // Bn*n0
    float* v1 = v0 + Bn * n0;        // Bn*n1
    float* e1 = v1 + Bn * n1;        // Bn*n1
    float* e2 = e1 + Bn * n1;        // Bn*n2
    float* T0 = e2 + Bn * n2;        // Bn*n0
    float* T1 = T0 + Bn * n0;        // Bn*n1
    float* tm = T1 + Bn * n1;        // n0   tanh(memory)
    float* r1 = tm + n0;             // n1   initial v1 row
    float* t1 = r1 + n1;             // n1   tanh(r1)
    float* r2 = t1 + n1;             // n2   initial pred2 row

    // ---- init (v0 rows identical => 1-row dots instead of full GEMMs) ----
    k_zero<<<1, 32, 0, stream>>>(out, 8);
    k_fill_v0<<<(Bn * n0) / 256, 256, 0, stream>>>(v0, memory, Bn * n0, n0 - 1);
    k_tanh<<<n0 / 256, 256, 0, stream>>>(tm, memory, n0);
    k_rowdot<<<n1, 256, 0, stream>>>(tm, W0, r1, n0);        // r1 = tanh(mem) @ W0^T
    k_tanh<<<n1 / 256, 256, 0, stream>>>(t1, r1, n1);
    k_bcast_v1_e1<<<(Bn * n1) / 256, 256, 0, stream>>>(v1, e1, r1, Bn * n1, n1 - 1);
    k_rowdot<<<n2, 256, 0, stream>>>(t1, W1, r2, n1);        // r2 = tanh(r1) @ W1^T
    k_e2_init<<<(Bn * n2) / 256, 256, 0, stream>>>(e2, batch_inp, r2, Bn * n2, n2 - 1);

    // ---- 8 inference iterations ----
    for (int it = 0; it < 8; ++it) {
        float* loss = out + it;
        // G1: e1 @ W0 (K=n1, N=n0) -> update v0, T0, Sum(ne0^2)
        gemm_fused<0, 1><<<dim3(n0 / 64, 4), 256, 0, stream>>>(
            e1, W0, n0, n1, v0, memory, v0, T0, loss, lr_ptr);
        // G2: e2 @ W1 (K=n2, N=n1) -> update v1, T1
        gemm_fused<0, 2><<<dim3(n1 / 64, 4), 256, 0, stream>>>(
            e2, W1, n1, n2, v1, e1, v1, T1, nullptr, lr_ptr);
        // G3: T0 @ W0^T (K=n0, N=n1) -> e1 = v1 - pred1, Sum(ne1^2)
        gemm_fused<1, 3><<<dim3(n1 / 64, 4), 256, 0, stream>>>(
            T0, W0, n1, n0, v1, nullptr, e1, nullptr, loss, nullptr);
        // G4: T1 @ W1^T (K=n1, N=n2) -> e2 = batch_inp - pred2, Sum(ne2^2)
        gemm_fused<1, 4><<<dim3(n2 / 64, 4), 256, 0, stream>>>(
            T1, W1, n2, n1, batch_inp, nullptr, e2, nullptr, loss, nullptr);
    }
}

// Round 2
// 2152.331 us; speedup vs baseline: 3.7580x; 3.7580x over previous
//
#include <hip/hip_runtime.h>
#include <hip/hip_bf16.h>
#include <stdint.h>

// MultilayerPCN: predictive-coding inference loop, bf16-MFMA version.
// NODES = [2048, 4096, 8192], B = 256, n_iters = 8 (hardcoded), LAMB = 0.5.
// Output: 8 fp32 energies.
//
// Per iteration (2 merged launches; G1/G2 independent, G3/G4 independent):
//   G1: c = e1 @ W0   -> nv0 = relu(v0 + lr*((mem-v0) - 0.5*sign(v0) + tanh'(v0)*c))
//                        T0b = bf16(tanh(nv0)); loss += sum((nv0-mem)^2)
//   G2: c = e2 @ W1   -> nv1 = relu(v1 + lr*(-e1 + tanh'(v1)*c)); T1b = bf16(tanh(nv1))
//   G3: c = T0 @ W0^T -> ne1 = v1 - c; e1 (f32+bf16); loss += sum(ne1^2)
//   G4: c = T1 @ W1^T -> ne2 = inp - c; e2b = bf16(ne2); loss += sum(ne2^2)
//
// GEMM: m97-style. BM=128, BN=64, BK=32; 256 thr (4 waves, 2x2);
// global_load_lds width-16 staging (no LDS padding — layout constraint);
// mfma_f32_16x16x32_bf16, 4x2 tiles/wave, fp32 accum.
// Weights cast per-call to bf16 in both orientations so every GEMM's B^T is
// N x K row-major (staging identical to A). ws use ~165 MB.

typedef short short8x __attribute__((ext_vector_type(8)));
typedef float float4x __attribute__((ext_vector_type(4)));
typedef unsigned short u16;

static constexpr float LOSS_SCALE = 100.0f / 256.0f;

__device__ __forceinline__ u16 f2b(float x) {
    union { float f; uint32_t u; } v{x};
    uint32_t b = v.u + 0x7fffu + ((v.u >> 16) & 1u);
    return (u16)(b >> 16);
}

__device__ __forceinline__ float signf_(float x) {
    return (x > 0.f) ? 1.f : ((x < 0.f) ? -1.f : 0.f);
}

__device__ __forceinline__ void gload_lds16(const void* g, void* lds) {
    __builtin_amdgcn_global_load_lds(
        (const __attribute__((address_space(1))) void*)g,
        (__attribute__((address_space(3))) void*)lds, 16, 0, 0);
}

// ---------------- init / cast kernels ----------------
__global__ void k_zero(float* p, int n) {
    int i = blockIdx.x * blockDim.x + threadIdx.x;
    if (i < n) p[i] = 0.f;
}

__global__ void k_cast(const float* __restrict__ in, u16* __restrict__ out, int n) {
    int i = blockIdx.x * blockDim.x + threadIdx.x;
    if (i < n) out[i] = f2b(in[i]);
}

// out (C x R bf16) = transpose(in (R x C f32))
__global__ __launch_bounds__(256) void k_transpose_cast(
    const float* __restrict__ in, u16* __restrict__ out, int R, int C) {
    __shared__ float tile[32][33];
    int x = blockIdx.x * 32 + threadIdx.x;
#pragma unroll
    for (int k = 0; k < 32; k += 8) {
        int y = blockIdx.y * 32 + threadIdx.y + k;
        tile[threadIdx.y + k][threadIdx.x] = in[(size_t)y * C + x];
    }
    __syncthreads();
    int ox = blockIdx.y * 32 + threadIdx.x;   // output col = input row
#pragma unroll
    for (int k = 0; k < 32; k += 8) {
        int oy = blockIdx.x * 32 + threadIdx.y + k;  // output row = input col
        out[(size_t)oy * R + ox] = f2b(tile[threadIdx.x][threadIdx.y + k]);
    }
}

__global__ void k_fill_v0(float* __restrict__ v0, const float* __restrict__ memory,
                          int n, int mask) {
    int i = blockIdx.x * blockDim.x + threadIdx.x;
    if (i < n) v0[i] = memory[i & mask];
}

__global__ void k_tanh(float* __restrict__ dst, const float* __restrict__ src, int n) {
    int i = blockIdx.x * blockDim.x + threadIdx.x;
    if (i < n) dst[i] = tanhf(src[i]);
}

// out[i] = sum_j x[j] * W[i*K + j]  (fp32, one block per output row; init only)
__global__ void k_rowdot(const float* __restrict__ x, const float* __restrict__ W,
                         float* __restrict__ out, int K) {
    int i = blockIdx.x;
    const float* w = W + (size_t)i * K;
    float s = 0.f;
    for (int j = threadIdx.x; j < K; j += 256) s += x[j] * w[j];
    __shared__ float red[256];
    red[threadIdx.x] = s;
    __syncthreads();
    for (int st = 128; st > 0; st >>= 1) {
        if (threadIdx.x < st) red[threadIdx.x] += red[threadIdx.x + st];
        __syncthreads();
    }
    if (threadIdx.x == 0) out[i] = red[0];
}

__global__ void k_bcast_v1_e1(float* __restrict__ v1, float* __restrict__ e1,
                              u16* __restrict__ e1b,
                              const float* __restrict__ r1, int n, int mask) {
    int i = blockIdx.x * blockDim.x + threadIdx.x;
    if (i < n) { v1[i] = r1[i & mask]; e1[i] = 0.f; e1b[i] = 0; }
}

__global__ void k_e2_init(u16* __restrict__ e2b, const float* __restrict__ inp,
                          const float* __restrict__ r2, int n, int mask) {
    int i = blockIdx.x * blockDim.x + threadIdx.x;
    if (i < n) e2b[i] = f2b(inp[i] - r2[i & mask]);
}

// ---------------- fused MFMA GEMM ----------------
struct GArgs {
    const u16* A;       // [256, K] bf16 row-major
    const u16* Bt;      // [N, K]  bf16 row-major (B transposed)
    const float* x0;    // epilogue input 0
    const float* x1;    // epilogue input 1
    float* y0;          // fp32 output (state)
    u16* y0b;           // bf16 copy of y0 (EPI3)
    u16* y1b;           // bf16 aux output (T0b/T1b/e2b)
    float* loss;        // atomic loss accumulator (nullptr for EPI2)
    const float* lr;    // inf_lr scalar (EPI1/2)
    int N, K, nCol;     // nCol = N/64
};

// BM=128, BN=64, BK=32. 256 threads = 4 waves in 2x2 (each wave 64x32).
template <int EPI>
__device__ void gemm_tile(const GArgs& g, int rowBlk, int colBlk,
                          u16* As /*4096 u16*/, u16* Bs /*2048 u16*/) {
    const int t = threadIdx.x;
    const int w = t >> 6, l = t & 63;
    const int row0 = rowBlk * 128, col0 = colBlk * 64;
    const int K = g.K;

    // staging: per-thread 16B; A tile 8KB (2 issues), B tile 4KB (1 issue)
    const int srow = t >> 2;                 // 0..63
    const int scolE = (t & 3) << 3;          // element offset 0/8/16/24
    const u16* aptr0 = g.A + (size_t)(row0 + srow) * K + scolE;
    const u16* aptr1 = g.A + (size_t)(row0 + 64 + srow) * K + scolE;
    const u16* bptr  = g.Bt + (size_t)(col0 + srow) * K + scolE;
    u16* alds0 = As + (w << 9);              // wave-uniform bases
    u16* alds1 = As + 2048 + (w << 9);
    u16* blds  = Bs + (w << 9);

    const int wm = (w >> 1) << 6;            // 0 / 64
    const int wn = (w & 1) << 5;             // 0 / 32
    const int lm = l & 15, lq = l >> 4;

    // LDS fragment offsets are k0-invariant
    int aoff[4], boff[2];
#pragma unroll
    for (int i = 0; i < 4; ++i) aoff[i] = (wm + i * 16 + lm) * 32 + lq * 8;
#pragma unroll
    for (int j = 0; j < 2; ++j) boff[j] = (wn + j * 16 + lm) * 32 + lq * 8;

    float4x acc[4][2];
#pragma unroll
    for (int i = 0; i < 4; ++i)
#pragma unroll
        for (int j = 0; j < 2; ++j) acc[i][j] = (float4x)0.f;

    for (int k0 = 0; k0 < K; k0 += 32) {
        gload_lds16(aptr0 + k0, alds0);
        gload_lds16(aptr1 + k0, alds1);
        gload_lds16(bptr + k0, blds);
        __syncthreads();
        short8x a[4], b[2];
#pragma unroll
        for (int i = 0; i < 4; ++i) a[i] = *(const short8x*)(As + aoff[i]);
#pragma unroll
        for (int j = 0; j < 2; ++j) b[j] = *(const short8x*)(Bs + boff[j]);
#pragma unroll
        for (int i = 0; i < 4; ++i)
#pragma unroll
            for (int j = 0; j < 2; ++j)
                acc[i][j] = __builtin_amdgcn_mfma_f32_16x16x32_bf16(a[i], b[j], acc[i][j], 0, 0, 0);
        __syncthreads();
    }

    // ---- fused epilogue ----
    // C/D layout: col = lane&15, row = (lane>>4)*4 + reg   [m89-verified]
    float lr = 0.f;
    if (EPI == 1 || EPI == 2) lr = *g.lr;
    float lsum = 0.f;

#pragma unroll
    for (int i = 0; i < 4; ++i) {
#pragma unroll
        for (int j = 0; j < 2; ++j) {
#pragma unroll
            for (int r = 0; r < 4; ++r) {
                const int m = row0 + wm + i * 16 + lq * 4 + r;
                const int n = col0 + wn + j * 16 + lm;
                const size_t idx = (size_t)m * g.N + n;
                const float c = acc[i][j][r];
                if (EPI == 1) {
                    float v = g.x0[idx];            // v0
                    float mem = g.x1[n];            // memory
                    float th = tanhf(v), td = 1.f - th * th;
                    float d0 = (mem - v) - 0.5f * signf_(v) + td * c;
                    float nv = v + lr * d0;
                    nv = nv > 0.f ? nv : 0.f;
                    g.y0[idx] = nv;                 // v0
                    g.y1b[idx] = f2b(tanhf(nv));    // T0b
                    float ne0 = nv - mem;
                    lsum += ne0 * ne0;
                } else if (EPI == 2) {
                    float v = g.x0[idx];            // v1
                    float e1v = g.x1[idx];          // e1 (pre-update)
                    float th = tanhf(v), td = 1.f - th * th;
                    float nv = v + lr * (-e1v + td * c);
                    nv = nv > 0.f ? nv : 0.f;
                    g.y0[idx] = nv;                 // v1
                    g.y1b[idx] = f2b(tanhf(nv));    // T1b
                } else if (EPI == 3) {
                    float ne1 = g.x0[idx] - c;      // v1 (updated) - pred1
                    g.y0[idx] = ne1;                // e1 f32
                    g.y0b[idx] = f2b(ne1);          // e1 bf16
                    lsum += ne1 * ne1;
                } else {
                    float ne2 = g.x0[idx] - c;      // batch_inp - pred2
                    g.y1b[idx] = f2b(ne2);          // e2 bf16
                    lsum += ne2 * ne2;
                }
            }
        }
    }

    if (EPI != 2) {
#pragma unroll
        for (int off = 32; off > 0; off >>= 1) lsum += __shfl_down(lsum, off);
        if (l == 0) atomicAdd(g.loss, lsum * LOSS_SCALE);
    }
}

template <int EPIA, int EPIB>
__global__ __launch_bounds__(256) void pcn_pair(GArgs ga, GArgs gb, int nBlocksA) {
    __shared__ u16 As[4096];   // 8 KB
    __shared__ u16 Bs[2048];   // 4 KB
    int bx = blockIdx.x;
    if (bx < nBlocksA) {
        gemm_tile<EPIA>(ga, bx / ga.nCol, bx % ga.nCol, As, Bs);
    } else {
        bx -= nBlocksA;
        gemm_tile<EPIB>(gb, bx / gb.nCol, bx % gb.nCol, As, Bs);
    }
}

extern "C" void kernel_launch(void* const* d_in, const int* in_sizes, int n_in,
                              void* d_out, int out_size, void* d_ws, size_t ws_size,
                              hipStream_t stream)
{
    const float* batch_inp = (const float*)d_in[0]; // (256, 8192)
    const float* W0        = (const float*)d_in[1]; // (4096, 2048)
    const float* W1        = (const float*)d_in[2]; // (8192, 4096)
    const float* memory    = (const float*)d_in[3]; // (2048,)
    const float* lr_ptr    = (const float*)d_in[5]; // 0.05
    float* out = (float*)d_out;                     // 8 losses

    const int n0 = 2048, n1 = 4096, n2 = 8192, Bn = 256;

    // ---- workspace layout (bytes) ----
    char* ws = (char*)d_ws;
    auto alloc_f = [&](size_t n) { float* p = (float*)ws; ws += n * 4; return p; };
    auto alloc_b = [&](size_t n) { u16* p = (u16*)ws; ws += n * 2; return p; };

    float* v0  = alloc_f((size_t)Bn * n0);
    float* v1  = alloc_f((size_t)Bn * n1);
    float* e1  = alloc_f((size_t)Bn * n1);
    u16*   e1b = alloc_b((size_t)Bn * n1);
    u16*   e2b = alloc_b((size_t)Bn * n2);
    u16*   T0b = alloc_b((size_t)Bn * n0);
    u16*   T1b = alloc_b((size_t)Bn * n1);
    u16*   W0b  = alloc_b((size_t)n1 * n0);   // (n1, n0)
    u16*   W0Tb = alloc_b((size_t)n0 * n1);   // (n0, n1)
    u16*   W1b  = alloc_b((size_t)n2 * n1);   // (n2, n1)
    u16*   W1Tb = alloc_b((size_t)n1 * n2);   // (n1, n2)
    float* tm = alloc_f(n0);
    float* r1 = alloc_f(n1);
    float* t1 = alloc_f(n1);
    float* r2 = alloc_f(n2);

    // ---- one-time init ----
    k_zero<<<1, 32, 0, stream>>>(out, 8);
    k_cast<<<(n1 * n0) / 256, 256, 0, stream>>>(W0, W0b, n1 * n0);
    k_cast<<<(n2 * n1) / 256, 256, 0, stream>>>(W1, W1b, n2 * n1);
    k_transpose_cast<<<dim3(n0 / 32, n1 / 32), dim3(32, 8), 0, stream>>>(W0, W0Tb, n1, n0);
    k_transpose_cast<<<dim3(n1 / 32, n2 / 32), dim3(32, 8), 0, stream>>>(W1, W1Tb, n2, n1);
    k_fill_v0<<<(Bn * n0) / 256, 256, 0, stream>>>(v0, memory, Bn * n0, n0 - 1);
    k_tanh<<<n0 / 256, 256, 0, stream>>>(tm, memory, n0);
    k_rowdot<<<n1, 256, 0, stream>>>(tm, W0, r1, n0);        // r1 = tanh(mem) @ W0^T
    k_tanh<<<n1 / 256, 256, 0, stream>>>(t1, r1, n1);
    k_bcast_v1_e1<<<(Bn * n1) / 256, 256, 0, stream>>>(v1, e1, e1b, r1, Bn * n1, n1 - 1);
    k_rowdot<<<n2, 256, 0, stream>>>(t1, W1, r2, n1);        // r2 = tanh(r1) @ W1^T
    k_e2_init<<<(Bn * n2) / 256, 256, 0, stream>>>(e2b, batch_inp, r2, Bn * n2, n2 - 1);

    // ---- 8 inference iterations ----
    for (int it = 0; it < 8; ++it) {
        float* loss = out + it;

        // pair 1: G2 (bigger, first) || G1
        GArgs g2{e2b, W1Tb, v1, e1, v1, nullptr, T1b, nullptr, lr_ptr,
                 n1, n2, n1 / 64};
        GArgs g1{e1b, W0Tb, v0, memory, v0, nullptr, T0b, loss, lr_ptr,
                 n0, n1, n0 / 64};
        int nG2 = 2 * (n1 / 64);   // 128
        int nG1 = 2 * (n0 / 64);   // 64
        pcn_pair<2, 1><<<nG2 + nG1, 256, 0, stream>>>(g2, g1, nG2);

        // pair 2: G4 (bigger, first) || G3
        GArgs g4{T1b, W1b, batch_inp, nullptr, nullptr, nullptr, e2b, loss, nullptr,
                 n2, n1, n2 / 64};
        GArgs g3{T0b, W0b, v1, nullptr, e1, e1b, nullptr, loss, nullptr,
                 n1, n0, n1 / 64};
        int nG4 = 2 * (n2 / 64);   // 256
        int nG3 = 2 * (n1 / 64);   // 128
        pcn_pair<4, 3><<<nG4 + nG3, 256, 0, stream>>>(g4, g3, nG4);
    }
}